// Round 1
// 1114.680 us; speedup vs baseline: 1.0671x; 1.0671x over previous
//
#include <hip/hip_runtime.h>
#include <math.h>

// Sizes: B=16, H=128, W=128, C=64, MODES=16, SCHMIDT=8, N_LAYERS=4
// h buffer: 16*128*128*64 = 16,777,216 floats (67 MB), updated in place per layer.

#define TWO_PI_128 0.049087385212340517f   // 2*pi/128
#define PI_4       0.78539816339744831f    // pi/4

// gelu(v) = 0.5 v (1 + tanh(u)), u = 0.79788456 v (1 + 0.044715 v^2)
//         = v * (1 - 1/(e^{2u} + 1))   -- ~10 VALU vs ~35 for libm tanhf
__device__ __forceinline__ float gelu_f(float v) {
  float ex = 1.5957691216057308f * v * fmaf(0.044715f, v * v, 1.0f);  // 2u
  float e = __expf(fminf(ex, 30.0f));      // clamp: avoid inf -> NaN in rcp
  float r = __builtin_amdgcn_rcpf(e + 1.0f);
  return fmaf(-v, r, v);
}

// h[pix][c4..c4+3] = x[pix][:3] @ w + b   (float4 over c: 4x fewer threads/instr)
__global__ __launch_bounds__(256) void k_fc_in(const float* __restrict__ x,
    const float* __restrict__ w, const float* __restrict__ b,
    float* __restrict__ h) {
  int t = blockIdx.x * 256 + threadIdx.x;   // over NPIX*16
  int pix = t >> 4, c4 = (t & 15) << 2;
  float x0 = x[pix * 3], x1 = x[pix * 3 + 1], x2 = x[pix * 3 + 2];
  float4 acc = *(const float4*)&b[c4];
  float4 w0 = *(const float4*)&w[c4];
  float4 w1 = *(const float4*)&w[64 + c4];
  float4 w2 = *(const float4*)&w[128 + c4];
  acc.x = fmaf(x2, w2.x, fmaf(x1, w1.x, fmaf(x0, w0.x, acc.x)));
  acc.y = fmaf(x2, w2.y, fmaf(x1, w1.y, fmaf(x0, w0.y, acc.y)));
  acc.z = fmaf(x2, w2.z, fmaf(x1, w1.z, fmaf(x0, w0.z, acc.z)));
  acc.w = fmaf(x2, w2.w, fmaf(x1, w1.w, fmaf(x0, w0.w, acc.w)));
  *(float4*)&h[(size_t)pix * 64 + c4] = acc;
}

// Fold Schmidt sum + 1/sqrt(8) + 1/(128*128) into complex weight,
// laid out for GEMM: Br/Bi[(n*64+c)*1024 + (m*64+o)]
__global__ __launch_bounds__(256) void k_prep(const float* __restrict__ wr,
    const float* __restrict__ wi, float* __restrict__ Br, float* __restrict__ Bi) {
  int t = blockIdx.x * 256 + threadIdx.x;     // linear over (m,n,c,o), o innermost
  int o = t & 63, c = (t >> 6) & 63, n = (t >> 12) & 15, m = t >> 16;
  const float4* pr = (const float4*)(wr) + (size_t)t * 2;
  float4 a = pr[0], d = pr[1];
  float sr = ((a.x + a.y) + (a.z + a.w)) + ((d.x + d.y) + (d.z + d.w));
  const float4* pi = (const float4*)(wi) + (size_t)t * 2;
  a = pi[0]; d = pi[1];
  float si = ((a.x + a.y) + (a.z + a.w)) + ((d.x + d.y) + (d.z + d.w));
  const float scale = 0.35355339059327373f / 16384.0f;  // 1/(sqrt(8)*128*128)
  int k = n * 64 + c, j = m * 64 + o;
  Br[k * 1024 + j] = sr * scale;
  Bi[k * 1024 + j] = si * scale;
}

// Forward truncated DFT along y (W axis): A1[b][x][ky][c], ky<16
__global__ __launch_bounds__(256) void k_dft_y(const float* __restrict__ h,
                                               float2* __restrict__ A1) {
  __shared__ float sh[128 * 64];
  int bx = blockIdx.x;                        // b*128 + x
  const float* src = h + (size_t)bx * 8192;
  for (int i = threadIdx.x; i < 2048; i += 256)
    *(float4*)&sh[i * 4] = *(const float4*)&src[i * 4];
  __syncthreads();
  int c = threadIdx.x & 63, kg = threadIdx.x >> 6;
  float cs[4], sn[4], wr_[4], wi_[4], sr[4], si[4];
  #pragma unroll
  for (int q = 0; q < 4; ++q) {
    int ky = kg + 4 * q;
    __sincosf(-TWO_PI_128 * (float)ky, &sn[q], &cs[q]);
    wr_[q] = 1.f; wi_[q] = 0.f; sr[q] = 0.f; si[q] = 0.f;
  }
  for (int y = 0; y < 128; ++y) {
    float hv = sh[y * 64 + c];
    #pragma unroll
    for (int q = 0; q < 4; ++q) {
      sr[q] = fmaf(hv, wr_[q], sr[q]);
      si[q] = fmaf(hv, wi_[q], si[q]);
      float nw = wr_[q] * cs[q] - wi_[q] * sn[q];
      wi_[q] = fmaf(wi_[q], cs[q], wr_[q] * sn[q]);
      wr_[q] = nw;
    }
  }
  #pragma unroll
  for (int q = 0; q < 4; ++q) {
    int ky = kg + 4 * q;
    A1[((size_t)bx * 16 + ky) * 64 + c] = make_float2(sr[q], si[q]);
  }
}

// Forward truncated DFT along x (H axis): rows (b*16+kx), cols (ky*64+c)
__global__ __launch_bounds__(256) void k_dft_x(const float2* __restrict__ A1,
    float* __restrict__ Ar, float* __restrict__ Ai) {
  __shared__ float2 sh[128 * 32];
  int b = blockIdx.x, ky = blockIdx.y, ch = blockIdx.z;
  int c0 = ch * 32;
  for (int i = threadIdx.x; i < 2048; i += 256) {
    int xx = i >> 4, u = (i & 15) * 2;
    *(float4*)&sh[xx * 32 + u] =
        *(const float4*)&A1[(((size_t)b * 128 + xx) * 16 + ky) * 64 + c0 + u];
  }
  __syncthreads();
  int cl = threadIdx.x & 31, kxg = threadIdx.x >> 5;
  float cs[2], sn[2], wr_[2], wi_[2], sr[2], si[2];
  #pragma unroll
  for (int q = 0; q < 2; ++q) {
    int kx = kxg + 8 * q;
    __sincosf(-TWO_PI_128 * (float)kx, &sn[q], &cs[q]);
    wr_[q] = 1.f; wi_[q] = 0.f; sr[q] = 0.f; si[q] = 0.f;
  }
  for (int xx = 0; xx < 128; ++xx) {
    float2 v = sh[xx * 32 + cl];
    #pragma unroll
    for (int q = 0; q < 2; ++q) {
      sr[q] = fmaf(v.x, wr_[q], sr[q]); sr[q] = fmaf(-v.y, wi_[q], sr[q]);
      si[q] = fmaf(v.x, wi_[q], si[q]); si[q] = fmaf(v.y, wr_[q], si[q]);
      float nw = wr_[q] * cs[q] - wi_[q] * sn[q];
      wi_[q] = fmaf(wi_[q], cs[q], wr_[q] * sn[q]);
      wr_[q] = nw;
    }
  }
  #pragma unroll
  for (int q = 0; q < 2; ++q) {
    int kx = kxg + 8 * q;
    int row = b * 16 + kx, col = ky * 64 + c0 + cl;
    Ar[row * 1024 + col] = sr[q];
    Ai[row * 1024 + col] = si[q];
  }
}

// Complex GEMM: C[256][1024] = A[256][1024] * B[1024][1024], K split in 2 (blockIdx.z)
__global__ __launch_bounds__(256) void k_gemm(const float* __restrict__ Ar,
    const float* __restrict__ Ai, const float* __restrict__ Br,
    const float* __restrict__ Bi, float2* __restrict__ Cp) {
  __shared__ float2 As[32][34];   // stride 34: float4-aligned rows (272 B)
  __shared__ float2 Bs[32][34];
  int tx = threadIdx.x & 15, ty = threadIdx.x >> 4;
  int row0 = blockIdx.y * 32, col0 = blockIdx.x * 32, kbase = blockIdx.z * 512;
  float cr00 = 0, cr01 = 0, cr10 = 0, cr11 = 0;
  float ci00 = 0, ci01 = 0, ci10 = 0, ci11 = 0;
  for (int kt = 0; kt < 512; kt += 32) {
    int k0 = kbase + kt;
    {
      int r = threadIdx.x >> 3, k4 = (threadIdx.x & 7) << 2;
      int gi = (row0 + r) * 1024 + k0 + k4;
      float4 ar = *(const float4*)&Ar[gi];
      float4 ai = *(const float4*)&Ai[gi];
      *(float4*)&As[r][k4]     = make_float4(ar.x, ai.x, ar.y, ai.y);
      *(float4*)&As[r][k4 + 2] = make_float4(ar.z, ai.z, ar.w, ai.w);
    }
    {
      int kk = threadIdx.x >> 3, j4 = (threadIdx.x & 7) << 2;
      int gi = (k0 + kk) * 1024 + col0 + j4;
      float4 br = *(const float4*)&Br[gi];
      float4 bi = *(const float4*)&Bi[gi];
      *(float4*)&Bs[kk][j4]     = make_float4(br.x, bi.x, br.y, bi.y);
      *(float4*)&Bs[kk][j4 + 2] = make_float4(br.z, bi.z, br.w, bi.w);
    }
    __syncthreads();
    #pragma unroll 8
    for (int kk = 0; kk < 32; ++kk) {
      float2 a0 = As[ty * 2][kk], a1 = As[ty * 2 + 1][kk];
      float2 b0 = Bs[kk][tx * 2], b1 = Bs[kk][tx * 2 + 1];
      cr00 = fmaf(a0.x, b0.x, cr00); cr00 = fmaf(-a0.y, b0.y, cr00);
      ci00 = fmaf(a0.x, b0.y, ci00); ci00 = fmaf(a0.y, b0.x, ci00);
      cr01 = fmaf(a0.x, b1.x, cr01); cr01 = fmaf(-a0.y, b1.y, cr01);
      ci01 = fmaf(a0.x, b1.y, ci01); ci01 = fmaf(a0.y, b1.x, ci01);
      cr10 = fmaf(a1.x, b0.x, cr10); cr10 = fmaf(-a1.y, b0.y, cr10);
      ci10 = fmaf(a1.x, b0.y, ci10); ci10 = fmaf(a1.y, b0.x, ci10);
      cr11 = fmaf(a1.x, b1.x, cr11); cr11 = fmaf(-a1.y, b1.y, cr11);
      ci11 = fmaf(a1.x, b1.y, ci11); ci11 = fmaf(a1.y, b1.x, ci11);
    }
    __syncthreads();
  }
  int r = row0 + ty * 2, jj = col0 + tx * 2;
  size_t base = ((size_t)blockIdx.z * 256 + r) * 1024 + jj;
  Cp[base]        = make_float2(cr00, ci00);
  Cp[base + 1]    = make_float2(cr01, ci01);
  Cp[base + 1024] = make_float2(cr10, ci10);
  Cp[base + 1025] = make_float2(cr11, ci11);
}

// Inverse DFT along the W-frequency axis m -> y. Sums the two K-split partials.
// T layout: [b][y][kx][c]
__global__ __launch_bounds__(256) void k_ifft_y(const float2* __restrict__ Cp,
                                                float2* __restrict__ T) {
  __shared__ float2 Cl[1024];
  int b = blockIdx.x >> 4, kx = blockIdx.x & 15;
  int row = b * 16 + kx;
  for (int i = threadIdx.x; i < 512; i += 256) {
    float4 u = *(const float4*)&Cp[(size_t)row * 1024 + i * 2];
    float4 v = *(const float4*)&Cp[(size_t)(256 + row) * 1024 + i * 2];
    *(float4*)&Cl[i * 2] = make_float4(u.x + v.x, u.y + v.y, u.z + v.z, u.w + v.w);
  }
  __syncthreads();
  int c = threadIdx.x & 63, yg = threadIdx.x >> 6;
  for (int y = yg; y < 128; y += 4) {
    float snv, csv;
    __sincosf(TWO_PI_128 * (float)y, &snv, &csv);
    float wr_ = 1.f, wi_ = 0.f, sr = 0.f, si = 0.f;
    #pragma unroll
    for (int ky = 0; ky < 16; ++ky) {
      float2 v = Cl[ky * 64 + c];
      sr = fmaf(v.x, wr_, sr); sr = fmaf(-v.y, wi_, sr);
      si = fmaf(v.x, wi_, si); si = fmaf(v.y, wr_, si);
      float nw = wr_ * csv - wi_ * snv;
      wi_ = fmaf(wi_, csv, wr_ * snv);
      wr_ = nw;
    }
    T[(((size_t)b * 128 + y) * 16 + kx) * 64 + c] = make_float2(sr, si);
  }
}

// Fused: inverse DFT along kx -> x (real part) + pointwise h@ww + wb + gelu.
// Block (b,y): reads/writes exactly the h elements at fixed (b,y).
// v2: hl LDS staging REMOVED -- x2's h reads are 4-address broadcasts, moved to
// the VMEM path (L1/L2-resident, 32 KB/block) to unload the CU-shared LDS port.
// __syncthreads() before the stores preserves the in-place read-before-write.
__global__ __launch_bounds__(256, 4) void k_layer_out(const float* hin,
    const float2* __restrict__ T, const float* __restrict__ ww,
    const float* __restrict__ wb, float* hout) {
  __shared__ alignas(16) float wwT[64 * 68];
  int b = blockIdx.x >> 7, y = blockIdx.x & 127;
  for (int i = threadIdx.x; i < 1024; i += 256) {
    int k = i >> 4, c4 = (i & 15) << 2;
    float4 v = *(const float4*)&ww[k * 64 + c4];
    wwT[(c4 + 0) * 68 + k] = v.x;
    wwT[(c4 + 1) * 68 + k] = v.y;
    wwT[(c4 + 2) * 68 + k] = v.z;
    wwT[(c4 + 3) * 68 + k] = v.w;
  }
  const float2* Tp = T + ((size_t)b * 128 + y) * 1024;
  __syncthreads();
  int ct = threadIdx.x & 15, xg = threadIdx.x >> 4;   // c = ct+16*cc, x = xg+16*j
  float acc[8][4];
  #pragma unroll
  for (int cc = 0; cc < 4; ++cc) {
    float bv = wb[ct + 16 * cc];
    #pragma unroll
    for (int j = 0; j < 8; ++j) acc[j][cc] = bv;
  }
  // x1: real part of sum_kx T[kx][c] * e^{+2pi i kx x/128}
  for (int kx = 0; kx < 16; ++kx) {
    float tr[4], ti[4];
    #pragma unroll
    for (int cc = 0; cc < 4; ++cc) {
      float2 v = Tp[kx * 64 + ct + 16 * cc];
      tr[cc] = v.x; ti[cc] = v.y;
    }
    float s0v, c0v, sst, cst;
    __sincosf(TWO_PI_128 * (float)(kx * xg), &s0v, &c0v);
    __sincosf(PI_4 * (float)kx, &sst, &cst);
    float wr_ = c0v, wi_ = s0v;
    #pragma unroll
    for (int j = 0; j < 8; ++j) {
      #pragma unroll
      for (int cc = 0; cc < 4; ++cc) {
        acc[j][cc] = fmaf(tr[cc], wr_, acc[j][cc]);
        acc[j][cc] = fmaf(-ti[cc], wi_, acc[j][cc]);
      }
      float nw = wr_ * cst - wi_ * sst;
      wi_ = fmaf(wi_, cst, wr_ * sst);
      wr_ = nw;
    }
  }
  // x2: h @ ww, h read directly from global (row x = xg+16*j at fixed y)
  const float* hrow = hin + (((size_t)b * 128 + xg) * 128 + y) * 64;
  #pragma unroll 1
  for (int kq = 0; kq < 64; kq += 4) {
    float4 wv[4];
    #pragma unroll
    for (int cc = 0; cc < 4; ++cc)
      wv[cc] = *(const float4*)&wwT[(ct + 16 * cc) * 68 + kq];
    #pragma unroll
    for (int j = 0; j < 8; ++j) {
      float4 hv = *(const float4*)&hrow[(size_t)j * 131072 + kq];  // 16*128*64
      #pragma unroll
      for (int cc = 0; cc < 4; ++cc) {
        acc[j][cc] = fmaf(hv.x, wv[cc].x, acc[j][cc]);
        acc[j][cc] = fmaf(hv.y, wv[cc].y, acc[j][cc]);
        acc[j][cc] = fmaf(hv.z, wv[cc].z, acc[j][cc]);
        acc[j][cc] = fmaf(hv.w, wv[cc].w, acc[j][cc]);
      }
    }
  }
  __syncthreads();   // all hin reads drained (barrier waits vmcnt) before stores
  #pragma unroll
  for (int j = 0; j < 8; ++j) {
    int xx = xg + 16 * j;
    size_t base = (((size_t)b * 128 + xx) * 128 + y) * 64 + ct;
    #pragma unroll
    for (int cc = 0; cc < 4; ++cc)
      hout[base + 16 * cc] = gelu_f(acc[j][cc]);
  }
}

// Fused fc1 + gelu + fc2.
// v3: h operand moved off LDS onto the VMEM path (double-buffered global float4
// loads; h rows are 4-address wave broadcasts, L2-resident). LDS keeps only w1T:
// 70.6 KB -> 35.8 KB, LDS instr/iter 16 -> 8 (was 1.5x over the CU-shared LDS
// port budget -> VALUBusy 63.7%), occupancy 2 -> 3 blocks/CU.
__global__ __launch_bounds__(256, 3) void k_final(const float* __restrict__ h,
    const float* __restrict__ w1, const float* __restrict__ b1,
    const float* __restrict__ w2, const float* __restrict__ b2,
    float* __restrict__ out) {
  __shared__ alignas(16) float w1T[128 * 68];   // w1T[j][k]
  __shared__ float b1s[128];
  __shared__ float w2s[128];
  for (int i = threadIdx.x; i < 2048; i += 256) {
    int k = i >> 5, j4 = (i & 31) << 2;
    float4 v = *(const float4*)&w1[k * 128 + j4];
    w1T[(j4 + 0) * 68 + k] = v.x;
    w1T[(j4 + 1) * 68 + k] = v.y;
    w1T[(j4 + 2) * 68 + k] = v.z;
    w1T[(j4 + 3) * 68 + k] = v.w;
  }
  if (threadIdx.x < 128) {
    b1s[threadIdx.x] = b1[threadIdx.x];
    w2s[threadIdx.x] = w2[threadIdx.x];
  }
  __syncthreads();
  int jt = threadIdx.x & 15, rg = threadIdx.x >> 4;  // j = jt+16*cc, r = rg+16*ii
  int r0 = blockIdx.x * 128;
  const float* hb = h + (size_t)(r0 + rg) * 64;      // row stride per ii: 16*64
  float acc[8][8];   // [ii][cc]
  #pragma unroll
  for (int cc = 0; cc < 8; ++cc) {
    float bv = b1s[jt + 16 * cc];
    #pragma unroll
    for (int ii = 0; ii < 8; ++ii) acc[ii][cc] = bv;
  }
  float4 hv[8], hn[8];
  #pragma unroll
  for (int ii = 0; ii < 8; ++ii) hv[ii] = *(const float4*)&hb[ii * 1024];

  auto fmab = [&](const float4* H, int kq) {
    #pragma unroll
    for (int cc = 0; cc < 8; ++cc) {
      float4 wv = *(const float4*)&w1T[(jt + 16 * cc) * 68 + kq];
      #pragma unroll
      for (int ii = 0; ii < 8; ++ii) {
        acc[ii][cc] = fmaf(H[ii].x, wv.x, acc[ii][cc]);
        acc[ii][cc] = fmaf(H[ii].y, wv.y, acc[ii][cc]);
        acc[ii][cc] = fmaf(H[ii].z, wv.z, acc[ii][cc]);
        acc[ii][cc] = fmaf(H[ii].w, wv.w, acc[ii][cc]);
      }
    }
  };
  #pragma unroll 1
  for (int kq = 0; kq < 64; kq += 8) {
    #pragma unroll
    for (int ii = 0; ii < 8; ++ii)
      hn[ii] = *(const float4*)&hb[ii * 1024 + kq + 4];
    fmab(hv, kq);
    #pragma unroll
    for (int ii = 0; ii < 8; ++ii)   // last iter reads 4 floats past the row:
      hv[ii] = *(const float4*)&hb[ii * 1024 + kq + 8];  // stays inside d_ws, unused
    fmab(hn, kq + 4);
  }
  float b2v = b2[0];
  #pragma unroll
  for (int ii = 0; ii < 8; ++ii) {
    float part = 0.f;
    #pragma unroll
    for (int cc = 0; cc < 8; ++cc)
      part = fmaf(gelu_f(acc[ii][cc]), w2s[jt + 16 * cc], part);
    part += __shfl_xor(part, 1, 64);
    part += __shfl_xor(part, 2, 64);
    part += __shfl_xor(part, 4, 64);
    part += __shfl_xor(part, 8, 64);
    if (jt == 0) out[r0 + rg + 16 * ii] = part + b2v;
  }
}

extern "C" void kernel_launch(void* const* d_in, const int* in_sizes, int n_in,
                              void* d_out, int out_size, void* d_ws, size_t ws_size,
                              hipStream_t stream) {
  (void)in_sizes; (void)n_in; (void)out_size; (void)ws_size;
  const float* x      = (const float*)d_in[0];
  const float* fcin_w = (const float*)d_in[1];
  const float* fcin_b = (const float*)d_in[2];
  const float* wr     = (const float*)d_in[3];
  const float* wi     = (const float*)d_in[4];
  const float* ww     = (const float*)d_in[5];
  const float* wb     = (const float*)d_in[6];
  const float* fc1_w  = (const float*)d_in[7];
  const float* fc1_b  = (const float*)d_in[8];
  const float* fc2_w  = (const float*)d_in[9];
  const float* fc2_b  = (const float*)d_in[10];
  float* out = (float*)d_out;

  // workspace layout (floats): total ~24.6M floats (~99 MB) -- unchanged
  float*  hA = (float*)d_ws;              // 16,777,216
  float2* A1 = (float2*)(hA + 16777216);  // 2,097,152 float2 (A1 fwd / T bwd alias)
  float*  Ar = (float*)(A1 + 2097152);    // 262,144
  float*  Ai = Ar + 262144;               // 262,144
  float*  Br = Ai + 262144;               // 1,048,576
  float*  Bi = Br + 1048576;              // 1,048,576
  float2* Cp = (float2*)(Bi + 1048576);   // 524,288 float2 (2 K-split partials)

  k_fc_in<<<16384, 256, 0, stream>>>(x, fcin_w, fcin_b, hA);
  for (int l = 0; l < 4; ++l) {
    k_prep<<<4096, 256, 0, stream>>>(wr + (size_t)l * 8388608,
                                     wi + (size_t)l * 8388608, Br, Bi);
    k_dft_y<<<2048, 256, 0, stream>>>(hA, A1);
    k_dft_x<<<dim3(16, 16, 2), 256, 0, stream>>>(A1, Ar, Ai);
    k_gemm<<<dim3(32, 8, 2), 256, 0, stream>>>(Ar, Ai, Br, Bi, Cp);
    k_ifft_y<<<256, 256, 0, stream>>>(Cp, A1);     // A1 now holds T
    k_layer_out<<<2048, 256, 0, stream>>>(hA, A1, ww + (size_t)l * 4096,
                                          wb + (size_t)l * 64, hA);
  }
  k_final<<<2048, 256, 0, stream>>>(hA, fc1_w, fc1_b, fc2_w, fc2_b, out);
}

// Round 2
// 1015.340 us; speedup vs baseline: 1.1715x; 1.0978x over previous
//
#include <hip/hip_runtime.h>
#include <math.h>

// Sizes: B=16, H=128, W=128, C=64, MODES=16, SCHMIDT=8, N_LAYERS=4
// h buffer: 16*128*128*64 = 16,777,216 floats (67 MB), updated in place per layer.

#define TWO_PI_128 0.049087385212340517f   // 2*pi/128
#define PI_4       0.78539816339744831f    // pi/4

// gelu(v) = 0.5 v (1 + tanh(u)), u = 0.79788456 v (1 + 0.044715 v^2)
//         = v * (1 - 1/(e^{2u} + 1))   -- ~10 VALU vs ~35 for libm tanhf
__device__ __forceinline__ float gelu_f(float v) {
  float ex = 1.5957691216057308f * v * fmaf(0.044715f, v * v, 1.0f);  // 2u
  float e = __expf(fminf(ex, 30.0f));      // clamp: avoid inf -> NaN in rcp
  float r = __builtin_amdgcn_rcpf(e + 1.0f);
  return fmaf(-v, r, v);
}

// h[pix][c4..c4+3] = x[pix][:3] @ w + b   (float4 over c)
__global__ __launch_bounds__(256) void k_fc_in(const float* __restrict__ x,
    const float* __restrict__ w, const float* __restrict__ b,
    float* __restrict__ h) {
  int t = blockIdx.x * 256 + threadIdx.x;   // over NPIX*16
  int pix = t >> 4, c4 = (t & 15) << 2;
  float x0 = x[pix * 3], x1 = x[pix * 3 + 1], x2 = x[pix * 3 + 2];
  float4 acc = *(const float4*)&b[c4];
  float4 w0 = *(const float4*)&w[c4];
  float4 w1 = *(const float4*)&w[64 + c4];
  float4 w2 = *(const float4*)&w[128 + c4];
  acc.x = fmaf(x2, w2.x, fmaf(x1, w1.x, fmaf(x0, w0.x, acc.x)));
  acc.y = fmaf(x2, w2.y, fmaf(x1, w1.y, fmaf(x0, w0.y, acc.y)));
  acc.z = fmaf(x2, w2.z, fmaf(x1, w1.z, fmaf(x0, w0.z, acc.z)));
  acc.w = fmaf(x2, w2.w, fmaf(x1, w1.w, fmaf(x0, w0.w, acc.w)));
  *(float4*)&h[(size_t)pix * 64 + c4] = acc;
}

// Fold Schmidt sum + 1/sqrt(8) + 1/(128*128) into complex weight,
// laid out for GEMM: Br/Bi[(n*64+c)*1024 + (m*64+o)]
__global__ __launch_bounds__(256) void k_prep(const float* __restrict__ wr,
    const float* __restrict__ wi, float* __restrict__ Br, float* __restrict__ Bi) {
  int t = blockIdx.x * 256 + threadIdx.x;     // linear over (m,n,c,o), o innermost
  int o = t & 63, c = (t >> 6) & 63, n = (t >> 12) & 15, m = t >> 16;
  const float4* pr = (const float4*)(wr) + (size_t)t * 2;
  float4 a = pr[0], d = pr[1];
  float sr = ((a.x + a.y) + (a.z + a.w)) + ((d.x + d.y) + (d.z + d.w));
  const float4* pi = (const float4*)(wi) + (size_t)t * 2;
  a = pi[0]; d = pi[1];
  float si = ((a.x + a.y) + (a.z + a.w)) + ((d.x + d.y) + (d.z + d.w));
  const float scale = 0.35355339059327373f / 16384.0f;  // 1/(sqrt(8)*128*128)
  int k = n * 64 + c, j = m * 64 + o;
  Br[k * 1024 + j] = sr * scale;
  Bi[k * 1024 + j] = si * scale;
}

// Forward truncated DFT along y (W axis): A1[b][x][ky][c], ky<16
// v2: radix-4 sub-accumulation. y = 4m+p: S_p = sum_m h[4m+p] * W4^m with
// W4 = e^{-i 4 th}; one twiddle recurrence per 4 samples instead of per sample
// (hot-loop VALU per (4y,q): 24 -> 12). Recombine: sum = Sum_p w^p S_p.
__global__ __launch_bounds__(256) void k_dft_y(const float* __restrict__ h,
                                               float2* __restrict__ A1) {
  __shared__ float sh[128 * 64];
  int bx = blockIdx.x;                        // b*128 + x
  const float* src = h + (size_t)bx * 8192;
  for (int i = threadIdx.x; i < 2048; i += 256)
    *(float4*)&sh[i * 4] = *(const float4*)&src[i * 4];
  __syncthreads();
  int c = threadIdx.x & 63, kg = threadIdx.x >> 6;
  float s4r[4][4], s4i[4][4];                 // [q][p]
  float w4r[4], w4i[4], c4t[4], s4t[4];
  #pragma unroll
  for (int q = 0; q < 4; ++q) {
    int ky = kg + 4 * q;
    __sincosf(-TWO_PI_128 * 4.0f * (float)ky, &s4t[q], &c4t[q]);
    w4r[q] = 1.f; w4i[q] = 0.f;
    #pragma unroll
    for (int p = 0; p < 4; ++p) { s4r[q][p] = 0.f; s4i[q][p] = 0.f; }
  }
  for (int m = 0; m < 32; ++m) {
    float hv[4];
    #pragma unroll
    for (int p = 0; p < 4; ++p) hv[p] = sh[(4 * m + p) * 64 + c];
    #pragma unroll
    for (int q = 0; q < 4; ++q) {
      #pragma unroll
      for (int p = 0; p < 4; ++p) {
        s4r[q][p] = fmaf(hv[p], w4r[q], s4r[q][p]);
        s4i[q][p] = fmaf(hv[p], w4i[q], s4i[q][p]);
      }
      float nw = w4r[q] * c4t[q] - w4i[q] * s4t[q];
      w4i[q] = fmaf(w4i[q], c4t[q], w4r[q] * s4t[q]);
      w4r[q] = nw;
    }
  }
  #pragma unroll
  for (int q = 0; q < 4; ++q) {
    int ky = kg + 4 * q;
    float s1, c1;
    __sincosf(-TWO_PI_128 * (float)ky, &s1, &c1);
    float sr = s4r[q][0], si = s4i[q][0];
    float wr_ = c1, wi_ = s1;
    #pragma unroll
    for (int p = 1; p < 4; ++p) {
      sr = fmaf(s4r[q][p], wr_, sr); sr = fmaf(-s4i[q][p], wi_, sr);
      si = fmaf(s4r[q][p], wi_, si); si = fmaf(s4i[q][p], wr_, si);
      float nw = wr_ * c1 - wi_ * s1;
      wi_ = fmaf(wi_, c1, wr_ * s1);
      wr_ = nw;
    }
    A1[((size_t)bx * 16 + ky) * 64 + c] = make_float2(sr, si);
  }
}

// Forward truncated DFT along x (H axis): rows (b*16+kx), cols (ky*64+c)
__global__ __launch_bounds__(256) void k_dft_x(const float2* __restrict__ A1,
    float* __restrict__ Ar, float* __restrict__ Ai) {
  __shared__ float2 sh[128 * 32];
  int b = blockIdx.x, ky = blockIdx.y, ch = blockIdx.z;
  int c0 = ch * 32;
  for (int i = threadIdx.x; i < 2048; i += 256) {
    int xx = i >> 4, u = (i & 15) * 2;
    *(float4*)&sh[xx * 32 + u] =
        *(const float4*)&A1[(((size_t)b * 128 + xx) * 16 + ky) * 64 + c0 + u];
  }
  __syncthreads();
  int cl = threadIdx.x & 31, kxg = threadIdx.x >> 5;
  float cs[2], sn[2], wr_[2], wi_[2], sr[2], si[2];
  #pragma unroll
  for (int q = 0; q < 2; ++q) {
    int kx = kxg + 8 * q;
    __sincosf(-TWO_PI_128 * (float)kx, &sn[q], &cs[q]);
    wr_[q] = 1.f; wi_[q] = 0.f; sr[q] = 0.f; si[q] = 0.f;
  }
  for (int xx = 0; xx < 128; ++xx) {
    float2 v = sh[xx * 32 + cl];
    #pragma unroll
    for (int q = 0; q < 2; ++q) {
      sr[q] = fmaf(v.x, wr_[q], sr[q]); sr[q] = fmaf(-v.y, wi_[q], sr[q]);
      si[q] = fmaf(v.x, wi_[q], si[q]); si[q] = fmaf(v.y, wr_[q], si[q]);
      float nw = wr_[q] * cs[q] - wi_[q] * sn[q];
      wi_[q] = fmaf(wi_[q], cs[q], wr_[q] * sn[q]);
      wr_[q] = nw;
    }
  }
  #pragma unroll
  for (int q = 0; q < 2; ++q) {
    int kx = kxg + 8 * q;
    int row = b * 16 + kx, col = ky * 64 + c0 + cl;
    Ar[row * 1024 + col] = sr[q];
    Ai[row * 1024 + col] = si[q];
  }
}

// Complex GEMM: C[256][1024] = A[256][1024] * B[1024][1024], K split in 2.
// v2: double-buffered LDS (T14-lite). Next K-tile's global loads are issued into
// registers BEFORE the compute phase, ds_write after the compute barrier -- HBM/L2
// latency hides under the 512-FMA inner loop instead of serializing behind it.
__global__ __launch_bounds__(256) void k_gemm(const float* __restrict__ Ar,
    const float* __restrict__ Ai, const float* __restrict__ Br,
    const float* __restrict__ Bi, float2* __restrict__ Cp) {
  __shared__ float2 As[2][32][34];
  __shared__ float2 Bs[2][32][34];
  int tx = threadIdx.x & 15, ty = threadIdx.x >> 4;
  int row0 = blockIdx.y * 32, col0 = blockIdx.x * 32, kbase = blockIdx.z * 512;
  int ra = threadIdx.x >> 3, k4 = (threadIdx.x & 7) << 2;  // stage coords
  float4 arv, aiv, brv, biv;
  float cr00 = 0, cr01 = 0, cr10 = 0, cr11 = 0;
  float ci00 = 0, ci01 = 0, ci10 = 0, ci11 = 0;
  // prologue: stage tile 0
  {
    int gia = (row0 + ra) * 1024 + kbase + k4;
    arv = *(const float4*)&Ar[gia];
    aiv = *(const float4*)&Ai[gia];
    int gib = (kbase + ra) * 1024 + col0 + k4;
    brv = *(const float4*)&Br[gib];
    biv = *(const float4*)&Bi[gib];
    *(float4*)&As[0][ra][k4]     = make_float4(arv.x, aiv.x, arv.y, aiv.y);
    *(float4*)&As[0][ra][k4 + 2] = make_float4(arv.z, aiv.z, arv.w, aiv.w);
    *(float4*)&Bs[0][ra][k4]     = make_float4(brv.x, biv.x, brv.y, biv.y);
    *(float4*)&Bs[0][ra][k4 + 2] = make_float4(brv.z, biv.z, brv.w, biv.w);
  }
  __syncthreads();
  for (int kt = 0; kt < 16; ++kt) {
    if (kt < 15) {                 // issue next-tile loads (overlap with compute)
      int k0 = kbase + (kt + 1) * 32;
      int gia = (row0 + ra) * 1024 + k0 + k4;
      arv = *(const float4*)&Ar[gia];
      aiv = *(const float4*)&Ai[gia];
      int gib = (k0 + ra) * 1024 + col0 + k4;
      brv = *(const float4*)&Br[gib];
      biv = *(const float4*)&Bi[gib];
    }
    int cur = kt & 1;
    #pragma unroll 8
    for (int kk = 0; kk < 32; ++kk) {
      float2 a0 = As[cur][ty * 2][kk], a1 = As[cur][ty * 2 + 1][kk];
      float2 b0 = Bs[cur][kk][tx * 2], b1 = Bs[cur][kk][tx * 2 + 1];
      cr00 = fmaf(a0.x, b0.x, cr00); cr00 = fmaf(-a0.y, b0.y, cr00);
      ci00 = fmaf(a0.x, b0.y, ci00); ci00 = fmaf(a0.y, b0.x, ci00);
      cr01 = fmaf(a0.x, b1.x, cr01); cr01 = fmaf(-a0.y, b1.y, cr01);
      ci01 = fmaf(a0.x, b1.y, ci01); ci01 = fmaf(a0.y, b1.x, ci01);
      cr10 = fmaf(a1.x, b0.x, cr10); cr10 = fmaf(-a1.y, b0.y, cr10);
      ci10 = fmaf(a1.x, b0.y, ci10); ci10 = fmaf(a1.y, b0.x, ci10);
      cr11 = fmaf(a1.x, b1.x, cr11); cr11 = fmaf(-a1.y, b1.y, cr11);
      ci11 = fmaf(a1.x, b1.y, ci11); ci11 = fmaf(a1.y, b1.x, ci11);
    }
    __syncthreads();               // all waves done reading As/Bs[cur^1] (kt-1)
    if (kt < 15) {
      int nxt = cur ^ 1;
      *(float4*)&As[nxt][ra][k4]     = make_float4(arv.x, aiv.x, arv.y, aiv.y);
      *(float4*)&As[nxt][ra][k4 + 2] = make_float4(arv.z, aiv.z, arv.w, aiv.w);
      *(float4*)&Bs[nxt][ra][k4]     = make_float4(brv.x, biv.x, brv.y, biv.y);
      *(float4*)&Bs[nxt][ra][k4 + 2] = make_float4(brv.z, biv.z, brv.w, biv.w);
    }
    __syncthreads();
  }
  int r = row0 + ty * 2, jj = col0 + tx * 2;
  size_t base = ((size_t)blockIdx.z * 256 + r) * 1024 + jj;
  Cp[base]        = make_float2(cr00, ci00);
  Cp[base + 1]    = make_float2(cr01, ci01);
  Cp[base + 1024] = make_float2(cr10, ci10);
  Cp[base + 1025] = make_float2(cr11, ci11);
}

// Inverse DFT along the W-frequency axis m -> y. Sums the two K-split partials.
// T layout: [b][y][kx][c]
__global__ __launch_bounds__(256) void k_ifft_y(const float2* __restrict__ Cp,
                                                float2* __restrict__ T) {
  __shared__ float2 Cl[1024];
  int b = blockIdx.x >> 4, kx = blockIdx.x & 15;
  int row = b * 16 + kx;
  for (int i = threadIdx.x; i < 512; i += 256) {
    float4 u = *(const float4*)&Cp[(size_t)row * 1024 + i * 2];
    float4 v = *(const float4*)&Cp[(size_t)(256 + row) * 1024 + i * 2];
    *(float4*)&Cl[i * 2] = make_float4(u.x + v.x, u.y + v.y, u.z + v.z, u.w + v.w);
  }
  __syncthreads();
  int c = threadIdx.x & 63, yg = threadIdx.x >> 6;
  for (int y = yg; y < 128; y += 4) {
    float snv, csv;
    __sincosf(TWO_PI_128 * (float)y, &snv, &csv);
    float wr_ = 1.f, wi_ = 0.f, sr = 0.f, si = 0.f;
    #pragma unroll
    for (int ky = 0; ky < 16; ++ky) {
      float2 v = Cl[ky * 64 + c];
      sr = fmaf(v.x, wr_, sr); sr = fmaf(-v.y, wi_, sr);
      si = fmaf(v.x, wi_, si); si = fmaf(v.y, wr_, si);
      float nw = wr_ * csv - wi_ * snv;
      wi_ = fmaf(wi_, csv, wr_ * snv);
      wr_ = nw;
    }
    T[(((size_t)b * 128 + y) * 16 + kx) * 64 + c] = make_float2(sr, si);
  }
}

// Fused: inverse DFT along kx -> x (real part) + pointwise h@ww + wb + gelu.
// Block (b,y): reads/writes exactly the h elements at fixed (b,y).
// hl LDS staging removed; x2's h reads are 4-address broadcasts on the VMEM path.
// __syncthreads() before the stores preserves the in-place read-before-write.
__global__ __launch_bounds__(256, 4) void k_layer_out(const float* hin,
    const float2* __restrict__ T, const float* __restrict__ ww,
    const float* __restrict__ wb, float* hout) {
  __shared__ alignas(16) float wwT[64 * 68];
  int b = blockIdx.x >> 7, y = blockIdx.x & 127;
  for (int i = threadIdx.x; i < 1024; i += 256) {
    int k = i >> 4, c4 = (i & 15) << 2;
    float4 v = *(const float4*)&ww[k * 64 + c4];
    wwT[(c4 + 0) * 68 + k] = v.x;
    wwT[(c4 + 1) * 68 + k] = v.y;
    wwT[(c4 + 2) * 68 + k] = v.z;
    wwT[(c4 + 3) * 68 + k] = v.w;
  }
  const float2* Tp = T + ((size_t)b * 128 + y) * 1024;
  __syncthreads();
  int ct = threadIdx.x & 15, xg = threadIdx.x >> 4;   // c = ct+16*cc, x = xg+16*j
  float acc[8][4];
  #pragma unroll
  for (int cc = 0; cc < 4; ++cc) {
    float bv = wb[ct + 16 * cc];
    #pragma unroll
    for (int j = 0; j < 8; ++j) acc[j][cc] = bv;
  }
  // x1: real part of sum_kx T[kx][c] * e^{+2pi i kx x/128}
  for (int kx = 0; kx < 16; ++kx) {
    float tr[4], ti[4];
    #pragma unroll
    for (int cc = 0; cc < 4; ++cc) {
      float2 v = Tp[kx * 64 + ct + 16 * cc];
      tr[cc] = v.x; ti[cc] = v.y;
    }
    float s0v, c0v, sst, cst;
    __sincosf(TWO_PI_128 * (float)(kx * xg), &s0v, &c0v);
    __sincosf(PI_4 * (float)kx, &sst, &cst);
    float wr_ = c0v, wi_ = s0v;
    #pragma unroll
    for (int j = 0; j < 8; ++j) {
      #pragma unroll
      for (int cc = 0; cc < 4; ++cc) {
        acc[j][cc] = fmaf(tr[cc], wr_, acc[j][cc]);
        acc[j][cc] = fmaf(-ti[cc], wi_, acc[j][cc]);
      }
      float nw = wr_ * cst - wi_ * sst;
      wi_ = fmaf(wi_, cst, wr_ * sst);
      wr_ = nw;
    }
  }
  // x2: h @ ww, h read directly from global (row x = xg+16*j at fixed y)
  const float* hrow = hin + (((size_t)b * 128 + xg) * 128 + y) * 64;
  #pragma unroll 1
  for (int kq = 0; kq < 64; kq += 4) {
    float4 wv[4];
    #pragma unroll
    for (int cc = 0; cc < 4; ++cc)
      wv[cc] = *(const float4*)&wwT[(ct + 16 * cc) * 68 + kq];
    #pragma unroll
    for (int j = 0; j < 8; ++j) {
      float4 hv = *(const float4*)&hrow[(size_t)j * 131072 + kq];  // 16*128*64
      #pragma unroll
      for (int cc = 0; cc < 4; ++cc) {
        acc[j][cc] = fmaf(hv.x, wv[cc].x, acc[j][cc]);
        acc[j][cc] = fmaf(hv.y, wv[cc].y, acc[j][cc]);
        acc[j][cc] = fmaf(hv.z, wv[cc].z, acc[j][cc]);
        acc[j][cc] = fmaf(hv.w, wv[cc].w, acc[j][cc]);
      }
    }
  }
  __syncthreads();   // all hin reads drained (barrier waits vmcnt) before stores
  #pragma unroll
  for (int j = 0; j < 8; ++j) {
    int xx = xg + 16 * j;
    size_t base = (((size_t)b * 128 + xx) * 128 + y) * 64 + ct;
    #pragma unroll
    for (int cc = 0; cc < 4; ++cc)
      hout[base + 16 * cc] = gelu_f(acc[j][cc]);
  }
}

// Fused fc1 + gelu + fc2.  (reverted to the measured-94us round-0 structure:
// hl+w1T both in LDS; hl reads are 4-address broadcasts, which the LDS serves
// nearly free -- moving them to VMEM regressed 94->108us with b128 2-way
// conflicts on w1T costing ~8 cyc/instr at higher concurrency.)
__global__ __launch_bounds__(256) void k_final(const float* __restrict__ h,
    const float* __restrict__ w1, const float* __restrict__ b1,
    const float* __restrict__ w2, const float* __restrict__ b2,
    float* __restrict__ out) {
  __shared__ alignas(16) float w1T[128 * 68];   // w1T[j][k]
  __shared__ alignas(16) float hl[128 * 68];    // hl[r][k]
  __shared__ float b1s[128];
  __shared__ float w2s[128];
  for (int i = threadIdx.x; i < 8192; i += 256) {
    int k = i >> 7, j = i & 127;
    w1T[j * 68 + k] = w1[i];
  }
  if (threadIdx.x < 128) {
    b1s[threadIdx.x] = b1[threadIdx.x];
    w2s[threadIdx.x] = w2[threadIdx.x];
  }
  int r0 = blockIdx.x * 128;
  for (int i = threadIdx.x; i < 2048; i += 256) {
    int r = i >> 4, kq = (i & 15) * 4;          // coalesced float4 row loads
    float4 v = *(const float4*)&h[(size_t)(r0 + r) * 64 + kq];
    *(float4*)&hl[r * 68 + kq] = v;
  }
  __syncthreads();
  int jt = threadIdx.x & 15, rg = threadIdx.x >> 4;  // j = jt+16*cc, r = rg+16*ii
  float acc[8][8];   // [ii][cc]
  #pragma unroll
  for (int cc = 0; cc < 8; ++cc) {
    float bv = b1s[jt + 16 * cc];
    #pragma unroll
    for (int ii = 0; ii < 8; ++ii) acc[ii][cc] = bv;
  }
  #pragma unroll 1
  for (int kq = 0; kq < 64; kq += 4) {
    float4 hv[8];
    #pragma unroll
    for (int ii = 0; ii < 8; ++ii)
      hv[ii] = *(const float4*)&hl[(rg + 16 * ii) * 68 + kq];
    #pragma unroll
    for (int cc = 0; cc < 8; ++cc) {
      float4 wv = *(const float4*)&w1T[(jt + 16 * cc) * 68 + kq];
      #pragma unroll
      for (int ii = 0; ii < 8; ++ii) {
        acc[ii][cc] = fmaf(hv[ii].x, wv.x, acc[ii][cc]);
        acc[ii][cc] = fmaf(hv[ii].y, wv.y, acc[ii][cc]);
        acc[ii][cc] = fmaf(hv[ii].z, wv.z, acc[ii][cc]);
        acc[ii][cc] = fmaf(hv[ii].w, wv.w, acc[ii][cc]);
      }
    }
  }
  float b2v = b2[0];
  #pragma unroll
  for (int ii = 0; ii < 8; ++ii) {
    float part = 0.f;
    #pragma unroll
    for (int cc = 0; cc < 8; ++cc)
      part = fmaf(gelu_f(acc[ii][cc]), w2s[jt + 16 * cc], part);
    part += __shfl_xor(part, 1, 64);
    part += __shfl_xor(part, 2, 64);
    part += __shfl_xor(part, 4, 64);
    part += __shfl_xor(part, 8, 64);
    if (jt == 0) out[r0 + rg + 16 * ii] = part + b2v;
  }
}

extern "C" void kernel_launch(void* const* d_in, const int* in_sizes, int n_in,
                              void* d_out, int out_size, void* d_ws, size_t ws_size,
                              hipStream_t stream) {
  (void)in_sizes; (void)n_in; (void)out_size; (void)ws_size;
  const float* x      = (const float*)d_in[0];
  const float* fcin_w = (const float*)d_in[1];
  const float* fcin_b = (const float*)d_in[2];
  const float* wr     = (const float*)d_in[3];
  const float* wi     = (const float*)d_in[4];
  const float* ww     = (const float*)d_in[5];
  const float* wb     = (const float*)d_in[6];
  const float* fc1_w  = (const float*)d_in[7];
  const float* fc1_b  = (const float*)d_in[8];
  const float* fc2_w  = (const float*)d_in[9];
  const float* fc2_b  = (const float*)d_in[10];
  float* out = (float*)d_out;

  // workspace layout (floats): total ~24.6M floats (~99 MB) -- unchanged
  float*  hA = (float*)d_ws;              // 16,777,216
  float2* A1 = (float2*)(hA + 16777216);  // 2,097,152 float2 (A1 fwd / T bwd alias)
  float*  Ar = (float*)(A1 + 2097152);    // 262,144
  float*  Ai = Ar + 262144;               // 262,144
  float*  Br = Ai + 262144;               // 1,048,576
  float*  Bi = Br + 1048576;              // 1,048,576
  float2* Cp = (float2*)(Bi + 1048576);   // 524,288 float2 (2 K-split partials)

  k_fc_in<<<16384, 256, 0, stream>>>(x, fcin_w, fcin_b, hA);
  for (int l = 0; l < 4; ++l) {
    k_prep<<<4096, 256, 0, stream>>>(wr + (size_t)l * 8388608,
                                     wi + (size_t)l * 8388608, Br, Bi);
    k_dft_y<<<2048, 256, 0, stream>>>(hA, A1);
    k_dft_x<<<dim3(16, 16, 2), 256, 0, stream>>>(A1, Ar, Ai);
    k_gemm<<<dim3(32, 8, 2), 256, 0, stream>>>(Ar, Ai, Br, Bi, Cp);
    k_ifft_y<<<256, 256, 0, stream>>>(Cp, A1);     // A1 now holds T
    k_layer_out<<<2048, 256, 0, stream>>>(hA, A1, ww + (size_t)l * 4096,
                                          wb + (size_t)l * 64, hA);
  }
  k_final<<<2048, 256, 0, stream>>>(hA, fc1_w, fc1_b, fc2_w, fc2_b, out);
}

// Round 3
// 1001.153 us; speedup vs baseline: 1.1881x; 1.0142x over previous
//
#include <hip/hip_runtime.h>
#include <math.h>

// Sizes: B=16, H=128, W=128, C=64, MODES=16, SCHMIDT=8, N_LAYERS=4
// h buffer: 16*128*128*64 = 16,777,216 floats (67 MB), updated in place per layer.

#define TWO_PI_128 0.049087385212340517f   // 2*pi/128

// gelu(v) = v * (1 - 1/(e^{2u} + 1)), u = 0.79788456 v (1 + 0.044715 v^2)
__device__ __forceinline__ float gelu_f(float v) {
  float ex = 1.5957691216057308f * v * fmaf(0.044715f, v * v, 1.0f);  // 2u
  float e = __expf(fminf(ex, 30.0f));      // clamp: avoid inf -> NaN in rcp
  float r = __builtin_amdgcn_rcpf(e + 1.0f);
  return fmaf(-v, r, v);
}

// h[pix][c4..c4+3] = x[pix][:3] @ w + b   (float4 over c)
__global__ __launch_bounds__(256) void k_fc_in(const float* __restrict__ x,
    const float* __restrict__ w, const float* __restrict__ b,
    float* __restrict__ h) {
  int t = blockIdx.x * 256 + threadIdx.x;   // over NPIX*16
  int pix = t >> 4, c4 = (t & 15) << 2;
  float x0 = x[pix * 3], x1 = x[pix * 3 + 1], x2 = x[pix * 3 + 2];
  float4 acc = *(const float4*)&b[c4];
  float4 w0 = *(const float4*)&w[c4];
  float4 w1 = *(const float4*)&w[64 + c4];
  float4 w2 = *(const float4*)&w[128 + c4];
  acc.x = fmaf(x2, w2.x, fmaf(x1, w1.x, fmaf(x0, w0.x, acc.x)));
  acc.y = fmaf(x2, w2.y, fmaf(x1, w1.y, fmaf(x0, w0.y, acc.y)));
  acc.z = fmaf(x2, w2.z, fmaf(x1, w1.z, fmaf(x0, w0.z, acc.z)));
  acc.w = fmaf(x2, w2.w, fmaf(x1, w1.w, fmaf(x0, w0.w, acc.w)));
  *(float4*)&h[(size_t)pix * 64 + c4] = acc;
}

// Fold Schmidt sum + 1/sqrt(8) + 1/(128*128) into complex weight,
// laid out for GEMM: Br/Bi[(n*64+c)*1024 + (m*64+o)]
__global__ __launch_bounds__(256) void k_prep(const float* __restrict__ wr,
    const float* __restrict__ wi, float* __restrict__ Br, float* __restrict__ Bi) {
  int t = blockIdx.x * 256 + threadIdx.x;     // linear over (m,n,c,o), o innermost
  int o = t & 63, c = (t >> 6) & 63, n = (t >> 12) & 15, m = t >> 16;
  const float4* pr = (const float4*)(wr) + (size_t)t * 2;
  float4 a = pr[0], d = pr[1];
  float sr = ((a.x + a.y) + (a.z + a.w)) + ((d.x + d.y) + (d.z + d.w));
  const float4* pi = (const float4*)(wi) + (size_t)t * 2;
  a = pi[0]; d = pi[1];
  float si = ((a.x + a.y) + (a.z + a.w)) + ((d.x + d.y) + (d.z + d.w));
  const float scale = 0.35355339059327373f / 16384.0f;  // 1/(sqrt(8)*128*128)
  int k = n * 64 + c, j = m * 64 + o;
  Br[k * 1024 + j] = sr * scale;
  Bi[k * 1024 + j] = si * scale;
}

// Forward truncated DFT along y (W axis): A1[b][x][ky][c], ky<16
// radix-4 sub-accumulation: one twiddle recurrence per 4 samples.
__global__ __launch_bounds__(256) void k_dft_y(const float* __restrict__ h,
                                               float2* __restrict__ A1) {
  __shared__ float sh[128 * 64];
  int bx = blockIdx.x;                        // b*128 + x
  const float* src = h + (size_t)bx * 8192;
  for (int i = threadIdx.x; i < 2048; i += 256)
    *(float4*)&sh[i * 4] = *(const float4*)&src[i * 4];
  __syncthreads();
  int c = threadIdx.x & 63, kg = threadIdx.x >> 6;
  float s4r[4][4], s4i[4][4];                 // [q][p]
  float w4r[4], w4i[4], c4t[4], s4t[4];
  #pragma unroll
  for (int q = 0; q < 4; ++q) {
    int ky = kg + 4 * q;
    __sincosf(-TWO_PI_128 * 4.0f * (float)ky, &s4t[q], &c4t[q]);
    w4r[q] = 1.f; w4i[q] = 0.f;
    #pragma unroll
    for (int p = 0; p < 4; ++p) { s4r[q][p] = 0.f; s4i[q][p] = 0.f; }
  }
  for (int m = 0; m < 32; ++m) {
    float hv[4];
    #pragma unroll
    for (int p = 0; p < 4; ++p) hv[p] = sh[(4 * m + p) * 64 + c];
    #pragma unroll
    for (int q = 0; q < 4; ++q) {
      #pragma unroll
      for (int p = 0; p < 4; ++p) {
        s4r[q][p] = fmaf(hv[p], w4r[q], s4r[q][p]);
        s4i[q][p] = fmaf(hv[p], w4i[q], s4i[q][p]);
      }
      float nw = w4r[q] * c4t[q] - w4i[q] * s4t[q];
      w4i[q] = fmaf(w4i[q], c4t[q], w4r[q] * s4t[q]);
      w4r[q] = nw;
    }
  }
  #pragma unroll
  for (int q = 0; q < 4; ++q) {
    int ky = kg + 4 * q;
    float s1, c1;
    __sincosf(-TWO_PI_128 * (float)ky, &s1, &c1);
    float sr = s4r[q][0], si = s4i[q][0];
    float wr_ = c1, wi_ = s1;
    #pragma unroll
    for (int p = 1; p < 4; ++p) {
      sr = fmaf(s4r[q][p], wr_, sr); sr = fmaf(-s4i[q][p], wi_, sr);
      si = fmaf(s4r[q][p], wi_, si); si = fmaf(s4i[q][p], wr_, si);
      float nw = wr_ * c1 - wi_ * s1;
      wi_ = fmaf(wi_, c1, wr_ * s1);
      wr_ = nw;
    }
    A1[((size_t)bx * 16 + ky) * 64 + c] = make_float2(sr, si);
  }
}

// Forward truncated DFT along x (H axis): rows (b*16+kx), cols (ky*64+c)
__global__ __launch_bounds__(256) void k_dft_x(const float2* __restrict__ A1,
    float* __restrict__ Ar, float* __restrict__ Ai) {
  __shared__ float2 sh[128 * 32];
  int b = blockIdx.x, ky = blockIdx.y, ch = blockIdx.z;
  int c0 = ch * 32;
  for (int i = threadIdx.x; i < 2048; i += 256) {
    int xx = i >> 4, u = (i & 15) * 2;
    *(float4*)&sh[xx * 32 + u] =
        *(const float4*)&A1[(((size_t)b * 128 + xx) * 16 + ky) * 64 + c0 + u];
  }
  __syncthreads();
  int cl = threadIdx.x & 31, kxg = threadIdx.x >> 5;
  float cs[2], sn[2], wr_[2], wi_[2], sr[2], si[2];
  #pragma unroll
  for (int q = 0; q < 2; ++q) {
    int kx = kxg + 8 * q;
    __sincosf(-TWO_PI_128 * (float)kx, &sn[q], &cs[q]);
    wr_[q] = 1.f; wi_[q] = 0.f; sr[q] = 0.f; si[q] = 0.f;
  }
  for (int xx = 0; xx < 128; ++xx) {
    float2 v = sh[xx * 32 + cl];
    #pragma unroll
    for (int q = 0; q < 2; ++q) {
      sr[q] = fmaf(v.x, wr_[q], sr[q]); sr[q] = fmaf(-v.y, wi_[q], sr[q]);
      si[q] = fmaf(v.x, wi_[q], si[q]); si[q] = fmaf(v.y, wr_[q], si[q]);
      float nw = wr_[q] * cs[q] - wi_[q] * sn[q];
      wi_[q] = fmaf(wi_[q], cs[q], wr_[q] * sn[q]);
      wr_[q] = nw;
    }
  }
  #pragma unroll
  for (int q = 0; q < 2; ++q) {
    int kx = kxg + 8 * q;
    int row = b * 16 + kx, col = ky * 64 + c0 + cl;
    Ar[row * 1024 + col] = sr[q];
    Ai[row * 1024 + col] = si[q];
  }
}

#define CMAC(cr, ci, ax, ay, bx, by)                 \
  cr = fmaf(ax, bx, cr); cr = fmaf(-(ay), by, cr);   \
  ci = fmaf(ax, by, ci); ci = fmaf(ay, bx, ci);

// Complex GEMM: C[256][1024] = A[256][1024] * B[1024][1024], K split in 2.
// Double-buffered LDS; v3: kk iterations paired into b128 LDS reads
// (As rows kk-contiguous, Bs rows j-contiguous) -> LDS instr count halved
// (was 2048 ds_read_b64/thread ~= 34us of CU-shared LDS port; LDS-bound).
__global__ __launch_bounds__(256) void k_gemm(const float* __restrict__ Ar,
    const float* __restrict__ Ai, const float* __restrict__ Br,
    const float* __restrict__ Bi, float2* __restrict__ Cp) {
  __shared__ float2 As[2][32][34];
  __shared__ float2 Bs[2][32][34];
  int tx = threadIdx.x & 15, ty = threadIdx.x >> 4;
  int row0 = blockIdx.y * 32, col0 = blockIdx.x * 32, kbase = blockIdx.z * 512;
  int ra = threadIdx.x >> 3, k4 = (threadIdx.x & 7) << 2;  // stage coords
  float4 arv, aiv, brv, biv;
  float cr00 = 0, cr01 = 0, cr10 = 0, cr11 = 0;
  float ci00 = 0, ci01 = 0, ci10 = 0, ci11 = 0;
  {
    int gia = (row0 + ra) * 1024 + kbase + k4;
    arv = *(const float4*)&Ar[gia];
    aiv = *(const float4*)&Ai[gia];
    int gib = (kbase + ra) * 1024 + col0 + k4;
    brv = *(const float4*)&Br[gib];
    biv = *(const float4*)&Bi[gib];
    *(float4*)&As[0][ra][k4]     = make_float4(arv.x, aiv.x, arv.y, aiv.y);
    *(float4*)&As[0][ra][k4 + 2] = make_float4(arv.z, aiv.z, arv.w, aiv.w);
    *(float4*)&Bs[0][ra][k4]     = make_float4(brv.x, biv.x, brv.y, biv.y);
    *(float4*)&Bs[0][ra][k4 + 2] = make_float4(brv.z, biv.z, brv.w, biv.w);
  }
  __syncthreads();
  for (int kt = 0; kt < 16; ++kt) {
    if (kt < 15) {                 // issue next-tile loads (overlap with compute)
      int k0 = kbase + (kt + 1) * 32;
      int gia = (row0 + ra) * 1024 + k0 + k4;
      arv = *(const float4*)&Ar[gia];
      aiv = *(const float4*)&Ai[gia];
      int gib = (k0 + ra) * 1024 + col0 + k4;
      brv = *(const float4*)&Br[gib];
      biv = *(const float4*)&Bi[gib];
    }
    int cur = kt & 1;
    #pragma unroll 8
    for (int kk2 = 0; kk2 < 16; ++kk2) {
      float4 a0p = *(const float4*)&As[cur][ty * 2][kk2 * 2];      // kk, kk+1
      float4 a1p = *(const float4*)&As[cur][ty * 2 + 1][kk2 * 2];
      float4 b0p = *(const float4*)&Bs[cur][kk2 * 2][tx * 2];      // j, j+1 @ kk
      float4 b1p = *(const float4*)&Bs[cur][kk2 * 2 + 1][tx * 2];  // j, j+1 @ kk+1
      CMAC(cr00, ci00, a0p.x, a0p.y, b0p.x, b0p.y)
      CMAC(cr01, ci01, a0p.x, a0p.y, b0p.z, b0p.w)
      CMAC(cr10, ci10, a1p.x, a1p.y, b0p.x, b0p.y)
      CMAC(cr11, ci11, a1p.x, a1p.y, b0p.z, b0p.w)
      CMAC(cr00, ci00, a0p.z, a0p.w, b1p.x, b1p.y)
      CMAC(cr01, ci01, a0p.z, a0p.w, b1p.z, b1p.w)
      CMAC(cr10, ci10, a1p.z, a1p.w, b1p.x, b1p.y)
      CMAC(cr11, ci11, a1p.z, a1p.w, b1p.z, b1p.w)
    }
    __syncthreads();               // all waves done reading buffer cur
    if (kt < 15) {
      int nxt = cur ^ 1;
      *(float4*)&As[nxt][ra][k4]     = make_float4(arv.x, aiv.x, arv.y, aiv.y);
      *(float4*)&As[nxt][ra][k4 + 2] = make_float4(arv.z, aiv.z, arv.w, aiv.w);
      *(float4*)&Bs[nxt][ra][k4]     = make_float4(brv.x, biv.x, brv.y, biv.y);
      *(float4*)&Bs[nxt][ra][k4 + 2] = make_float4(brv.z, biv.z, brv.w, biv.w);
    }
    __syncthreads();
  }
  int r = row0 + ty * 2, jj = col0 + tx * 2;
  size_t base = ((size_t)blockIdx.z * 256 + r) * 1024 + jj;
  Cp[base]        = make_float2(cr00, ci00);
  Cp[base + 1]    = make_float2(cr01, ci01);
  Cp[base + 1024] = make_float2(cr10, ci10);
  Cp[base + 1025] = make_float2(cr11, ci11);
}

// Inverse DFT along the W-frequency axis m -> y. Sums the two K-split partials.
// T layout: [b][y][kx][c]
__global__ __launch_bounds__(256) void k_ifft_y(const float2* __restrict__ Cp,
                                                float2* __restrict__ T) {
  __shared__ float2 Cl[1024];
  int b = blockIdx.x >> 4, kx = blockIdx.x & 15;
  int row = b * 16 + kx;
  for (int i = threadIdx.x; i < 512; i += 256) {
    float4 u = *(const float4*)&Cp[(size_t)row * 1024 + i * 2];
    float4 v = *(const float4*)&Cp[(size_t)(256 + row) * 1024 + i * 2];
    *(float4*)&Cl[i * 2] = make_float4(u.x + v.x, u.y + v.y, u.z + v.z, u.w + v.w);
  }
  __syncthreads();
  int c = threadIdx.x & 63, yg = threadIdx.x >> 6;
  for (int y = yg; y < 128; y += 4) {
    float snv, csv;
    __sincosf(TWO_PI_128 * (float)y, &snv, &csv);
    float wr_ = 1.f, wi_ = 0.f, sr = 0.f, si = 0.f;
    #pragma unroll
    for (int ky = 0; ky < 16; ++ky) {
      float2 v = Cl[ky * 64 + c];
      sr = fmaf(v.x, wr_, sr); sr = fmaf(-v.y, wi_, sr);
      si = fmaf(v.x, wi_, si); si = fmaf(v.y, wr_, si);
      float nw = wr_ * csv - wi_ * snv;
      wi_ = fmaf(wi_, csv, wr_ * snv);
      wr_ = nw;
    }
    T[(((size_t)b * 128 + y) * 16 + kx) * 64 + c] = make_float2(sr, si);
  }
}

// Fused: inverse DFT along kx -> x (real part) + pointwise h@ww + wb + gelu.
// Block (b,y): reads/writes exactly the h elements at fixed (b,y).
// v3 remap: ct in [0,8) (8 cc), xg in [0,32) (4 j), x = xg + 32*j.
// Per-j twiddle step is e^{2pi i kx*32/128} = i^kx -> compile-time swap/negate
// (eliminates the 6-op rotation recurrence, ~768 VALU/thread). hv global loads:
// 8 distinct addrs x 16B = 128B/wave-instr (2x coalescing) and half the count.
__global__ __launch_bounds__(256, 4) void k_layer_out(const float* hin,
    const float2* __restrict__ T, const float* __restrict__ ww,
    const float* __restrict__ wb, float* hout) {
  __shared__ alignas(16) float wwT[64 * 68];
  int b = blockIdx.x >> 7, y = blockIdx.x & 127;
  for (int i = threadIdx.x; i < 1024; i += 256) {
    int k = i >> 4, c4 = (i & 15) << 2;
    float4 v = *(const float4*)&ww[k * 64 + c4];
    wwT[(c4 + 0) * 68 + k] = v.x;
    wwT[(c4 + 1) * 68 + k] = v.y;
    wwT[(c4 + 2) * 68 + k] = v.z;
    wwT[(c4 + 3) * 68 + k] = v.w;
  }
  const float2* Tp = T + ((size_t)b * 128 + y) * 1024;
  __syncthreads();
  int ct = threadIdx.x & 7, xg = threadIdx.x >> 3;  // c = ct+8cc, x = xg+32j
  float acc[4][8];
  #pragma unroll
  for (int cc = 0; cc < 8; ++cc) {
    float bv = wb[ct + 8 * cc];
    #pragma unroll
    for (int j = 0; j < 4; ++j) acc[j][cc] = bv;
  }
  // x1: real part of sum_kx T[kx][c] * e^{+2pi i kx x/128}
  #pragma unroll
  for (int kx = 0; kx < 16; ++kx) {
    float tr[8], ti[8];
    #pragma unroll
    for (int cc = 0; cc < 8; ++cc) {
      float2 v = Tp[kx * 64 + ct + 8 * cc];
      tr[cc] = v.x; ti[cc] = v.y;
    }
    float s0v, c0v;
    __sincosf(TWO_PI_128 * (float)(kx * xg), &s0v, &c0v);
    float wr_ = c0v, wi_ = s0v;
    #pragma unroll
    for (int j = 0; j < 4; ++j) {
      #pragma unroll
      for (int cc = 0; cc < 8; ++cc) {
        acc[j][cc] = fmaf(tr[cc], wr_, acc[j][cc]);
        acc[j][cc] = fmaf(-ti[cc], wi_, acc[j][cc]);
      }
      // rotate (wr,wi) by i^kx -- kx is unroll-constant, folds at compile time
      float owr = wr_, owi = wi_;
      if ((kx & 3) == 1)      { wr_ = -owi; wi_ =  owr; }
      else if ((kx & 3) == 2) { wr_ = -owr; wi_ = -owi; }
      else if ((kx & 3) == 3) { wr_ =  owi; wi_ = -owr; }
    }
  }
  // x2: h @ ww, h read directly from global (rows x = xg+32j at fixed y)
  const float* hp = hin + (((size_t)b * 128 + xg) * 128 + y) * 64;
  #pragma unroll 1
  for (int kq = 0; kq < 64; kq += 4) {
    float4 wv[8];
    #pragma unroll
    for (int cc = 0; cc < 8; ++cc)
      wv[cc] = *(const float4*)&wwT[(ct + 8 * cc) * 68 + kq];
    #pragma unroll
    for (int j = 0; j < 4; ++j) {
      float4 hv = *(const float4*)&hp[(size_t)j * 262144 + kq];  // 32*128*64
      #pragma unroll
      for (int cc = 0; cc < 8; ++cc) {
        acc[j][cc] = fmaf(hv.x, wv[cc].x, acc[j][cc]);
        acc[j][cc] = fmaf(hv.y, wv[cc].y, acc[j][cc]);
        acc[j][cc] = fmaf(hv.z, wv[cc].z, acc[j][cc]);
        acc[j][cc] = fmaf(hv.w, wv[cc].w, acc[j][cc]);
      }
    }
  }
  __syncthreads();   // all hin reads drained (barrier waits vmcnt) before stores
  #pragma unroll
  for (int j = 0; j < 4; ++j) {
    int xx = xg + 32 * j;
    size_t base = (((size_t)b * 128 + xx) * 128 + y) * 64 + ct;
    #pragma unroll
    for (int cc = 0; cc < 8; ++cc)
      hout[base + 8 * cc] = gelu_f(acc[j][cc]);
  }
}

// Fused fc1 + gelu + fc2.
// v4: 64-row blocks (grid 4096). LDS 70.6 KB -> 53.2 KB = 3 blocks/CU
// (occupancy cap 19.5% -> 37.5%); k_final was occupancy-capped at 2 blocks.
__global__ __launch_bounds__(256) void k_final(const float* __restrict__ h,
    const float* __restrict__ w1, const float* __restrict__ b1,
    const float* __restrict__ w2, const float* __restrict__ b2,
    float* __restrict__ out) {
  __shared__ alignas(16) float w1T[128 * 68];   // w1T[j][k] 34816 B
  __shared__ alignas(16) float hl[64 * 68];     // hl[r][k]  17408 B
  __shared__ float b1s[128];
  __shared__ float w2s[128];
  for (int i = threadIdx.x; i < 8192; i += 256) {
    int k = i >> 7, j = i & 127;
    w1T[j * 68 + k] = w1[i];
  }
  if (threadIdx.x < 128) {
    b1s[threadIdx.x] = b1[threadIdx.x];
    w2s[threadIdx.x] = w2[threadIdx.x];
  }
  int r0 = blockIdx.x * 64;
  for (int i = threadIdx.x; i < 1024; i += 256) {
    int r = i >> 4, kq = (i & 15) * 4;          // coalesced float4 row loads
    float4 v = *(const float4*)&h[(size_t)(r0 + r) * 64 + kq];
    *(float4*)&hl[r * 68 + kq] = v;
  }
  __syncthreads();
  int jt = threadIdx.x & 15, rg = threadIdx.x >> 4;  // j = jt+16*cc, r = rg+16*ii
  float acc[4][8];   // [ii][cc]
  #pragma unroll
  for (int cc = 0; cc < 8; ++cc) {
    float bv = b1s[jt + 16 * cc];
    #pragma unroll
    for (int ii = 0; ii < 4; ++ii) acc[ii][cc] = bv;
  }
  #pragma unroll 1
  for (int kq = 0; kq < 64; kq += 4) {
    float4 hv[4];
    #pragma unroll
    for (int ii = 0; ii < 4; ++ii)
      hv[ii] = *(const float4*)&hl[(rg + 16 * ii) * 68 + kq];
    #pragma unroll
    for (int cc = 0; cc < 8; ++cc) {
      float4 wv = *(const float4*)&w1T[(jt + 16 * cc) * 68 + kq];
      #pragma unroll
      for (int ii = 0; ii < 4; ++ii) {
        acc[ii][cc] = fmaf(hv[ii].x, wv.x, acc[ii][cc]);
        acc[ii][cc] = fmaf(hv[ii].y, wv.y, acc[ii][cc]);
        acc[ii][cc] = fmaf(hv[ii].z, wv.z, acc[ii][cc]);
        acc[ii][cc] = fmaf(hv[ii].w, wv.w, acc[ii][cc]);
      }
    }
  }
  float b2v = b2[0];
  #pragma unroll
  for (int ii = 0; ii < 4; ++ii) {
    float part = 0.f;
    #pragma unroll
    for (int cc = 0; cc < 8; ++cc)
      part = fmaf(gelu_f(acc[ii][cc]), w2s[jt + 16 * cc], part);
    part += __shfl_xor(part, 1, 64);
    part += __shfl_xor(part, 2, 64);
    part += __shfl_xor(part, 4, 64);
    part += __shfl_xor(part, 8, 64);
    if (jt == 0) out[r0 + rg + 16 * ii] = part + b2v;
  }
}

extern "C" void kernel_launch(void* const* d_in, const int* in_sizes, int n_in,
                              void* d_out, int out_size, void* d_ws, size_t ws_size,
                              hipStream_t stream) {
  (void)in_sizes; (void)n_in; (void)out_size; (void)ws_size;
  const float* x      = (const float*)d_in[0];
  const float* fcin_w = (const float*)d_in[1];
  const float* fcin_b = (const float*)d_in[2];
  const float* wr     = (const float*)d_in[3];
  const float* wi     = (const float*)d_in[4];
  const float* ww     = (const float*)d_in[5];
  const float* wb     = (const float*)d_in[6];
  const float* fc1_w  = (const float*)d_in[7];
  const float* fc1_b  = (const float*)d_in[8];
  const float* fc2_w  = (const float*)d_in[9];
  const float* fc2_b  = (const float*)d_in[10];
  float* out = (float*)d_out;

  // workspace layout (floats): total ~24.6M floats (~99 MB) -- unchanged
  float*  hA = (float*)d_ws;              // 16,777,216
  float2* A1 = (float2*)(hA + 16777216);  // 2,097,152 float2 (A1 fwd / T bwd alias)
  float*  Ar = (float*)(A1 + 2097152);    // 262,144
  float*  Ai = Ar + 262144;               // 262,144
  float*  Br = Ai + 262144;               // 1,048,576
  float*  Bi = Br + 1048576;              // 1,048,576
  float2* Cp = (float2*)(Bi + 1048576);   // 524,288 float2 (2 K-split partials)

  k_fc_in<<<16384, 256, 0, stream>>>(x, fcin_w, fcin_b, hA);
  for (int l = 0; l < 4; ++l) {
    k_prep<<<4096, 256, 0, stream>>>(wr + (size_t)l * 8388608,
                                     wi + (size_t)l * 8388608, Br, Bi);
    k_dft_y<<<2048, 256, 0, stream>>>(hA, A1);
    k_dft_x<<<dim3(16, 16, 2), 256, 0, stream>>>(A1, Ar, Ai);
    k_gemm<<<dim3(32, 8, 2), 256, 0, stream>>>(Ar, Ai, Br, Bi, Cp);
    k_ifft_y<<<256, 256, 0, stream>>>(Cp, A1);     // A1 now holds T
    k_layer_out<<<2048, 256, 0, stream>>>(hA, A1, ww + (size_t)l * 4096,
                                          wb + (size_t)l * 64, hA);
  }
  k_final<<<4096, 256, 0, stream>>>(hA, fc1_w, fc1_b, fc2_w, fc2_b, out);
}

// Round 5
// 994.289 us; speedup vs baseline: 1.1963x; 1.0069x over previous
//
#include <hip/hip_runtime.h>
#include <math.h>

// Sizes: B=16, H=128, W=128, C=64, MODES=16, SCHMIDT=8, N_LAYERS=4
// h buffer: 16*128*128*64 = 16,777,216 floats (67 MB), updated in place per layer.

#define TWO_PI_128 0.049087385212340517f   // 2*pi/128

// gelu(v) = v * (1 - 1/(e^{2u} + 1)), u = 0.79788456 v (1 + 0.044715 v^2)
__device__ __forceinline__ float gelu_f(float v) {
  float ex = 1.5957691216057308f * v * fmaf(0.044715f, v * v, 1.0f);  // 2u
  float e = __expf(fminf(ex, 30.0f));      // clamp: avoid inf -> NaN in rcp
  float r = __builtin_amdgcn_rcpf(e + 1.0f);
  return fmaf(-v, r, v);
}

// h[pix][c4..c4+3] = x[pix][:3] @ w + b   (float4 over c)
__global__ __launch_bounds__(256) void k_fc_in(const float* __restrict__ x,
    const float* __restrict__ w, const float* __restrict__ b,
    float* __restrict__ h) {
  int t = blockIdx.x * 256 + threadIdx.x;   // over NPIX*16
  int pix = t >> 4, c4 = (t & 15) << 2;
  float x0 = x[pix * 3], x1 = x[pix * 3 + 1], x2 = x[pix * 3 + 2];
  float4 acc = *(const float4*)&b[c4];
  float4 w0 = *(const float4*)&w[c4];
  float4 w1 = *(const float4*)&w[64 + c4];
  float4 w2 = *(const float4*)&w[128 + c4];
  acc.x = fmaf(x2, w2.x, fmaf(x1, w1.x, fmaf(x0, w0.x, acc.x)));
  acc.y = fmaf(x2, w2.y, fmaf(x1, w1.y, fmaf(x0, w0.y, acc.y)));
  acc.z = fmaf(x2, w2.z, fmaf(x1, w1.z, fmaf(x0, w0.z, acc.z)));
  acc.w = fmaf(x2, w2.w, fmaf(x1, w1.w, fmaf(x0, w0.w, acc.w)));
  *(float4*)&h[(size_t)pix * 64 + c4] = acc;
}

// Fold Schmidt sum + 1/sqrt(8) + 1/(128*128) into complex weight,
// laid out for GEMM: Br/Bi[(n*64+c)*1024 + (m*64+o)]
__global__ __launch_bounds__(256) void k_prep(const float* __restrict__ wr,
    const float* __restrict__ wi, float* __restrict__ Br, float* __restrict__ Bi) {
  int t = blockIdx.x * 256 + threadIdx.x;     // linear over (m,n,c,o), o innermost
  int o = t & 63, c = (t >> 6) & 63, n = (t >> 12) & 15, m = t >> 16;
  const float4* pr = (const float4*)(wr) + (size_t)t * 2;
  float4 a = pr[0], d = pr[1];
  float sr = ((a.x + a.y) + (a.z + a.w)) + ((d.x + d.y) + (d.z + d.w));
  const float4* pi = (const float4*)(wi) + (size_t)t * 2;
  a = pi[0]; d = pi[1];
  float si = ((a.x + a.y) + (a.z + a.w)) + ((d.x + d.y) + (d.z + d.w));
  const float scale = 0.35355339059327373f / 16384.0f;  // 1/(sqrt(8)*128*128)
  int k = n * 64 + c, j = m * 64 + o;
  Br[k * 1024 + j] = sr * scale;
  Bi[k * 1024 + j] = si * scale;
}

// Forward truncated DFT along y (W axis): A1[b][x][ky][c], ky<16
// radix-4 sub-accumulation: one twiddle recurrence per 4 samples.
__global__ __launch_bounds__(256) void k_dft_y(const float* __restrict__ h,
                                               float2* __restrict__ A1) {
  __shared__ float sh[128 * 64];
  int bx = blockIdx.x;                        // b*128 + x
  const float* src = h + (size_t)bx * 8192;
  for (int i = threadIdx.x; i < 2048; i += 256)
    *(float4*)&sh[i * 4] = *(const float4*)&src[i * 4];
  __syncthreads();
  int c = threadIdx.x & 63, kg = threadIdx.x >> 6;
  float s4r[4][4], s4i[4][4];                 // [q][p]
  float w4r[4], w4i[4], c4t[4], s4t[4];
  #pragma unroll
  for (int q = 0; q < 4; ++q) {
    int ky = kg + 4 * q;
    __sincosf(-TWO_PI_128 * 4.0f * (float)ky, &s4t[q], &c4t[q]);
    w4r[q] = 1.f; w4i[q] = 0.f;
    #pragma unroll
    for (int p = 0; p < 4; ++p) { s4r[q][p] = 0.f; s4i[q][p] = 0.f; }
  }
  for (int m = 0; m < 32; ++m) {
    float hv[4];
    #pragma unroll
    for (int p = 0; p < 4; ++p) hv[p] = sh[(4 * m + p) * 64 + c];
    #pragma unroll
    for (int q = 0; q < 4; ++q) {
      #pragma unroll
      for (int p = 0; p < 4; ++p) {
        s4r[q][p] = fmaf(hv[p], w4r[q], s4r[q][p]);
        s4i[q][p] = fmaf(hv[p], w4i[q], s4i[q][p]);
      }
      float nw = w4r[q] * c4t[q] - w4i[q] * s4t[q];
      w4i[q] = fmaf(w4i[q], c4t[q], w4r[q] * s4t[q]);
      w4r[q] = nw;
    }
  }
  #pragma unroll
  for (int q = 0; q < 4; ++q) {
    int ky = kg + 4 * q;
    float s1, c1;
    __sincosf(-TWO_PI_128 * (float)ky, &s1, &c1);
    float sr = s4r[q][0], si = s4i[q][0];
    float wr_ = c1, wi_ = s1;
    #pragma unroll
    for (int p = 1; p < 4; ++p) {
      sr = fmaf(s4r[q][p], wr_, sr); sr = fmaf(-s4i[q][p], wi_, sr);
      si = fmaf(s4r[q][p], wi_, si); si = fmaf(s4i[q][p], wr_, si);
      float nw = wr_ * c1 - wi_ * s1;
      wi_ = fmaf(wi_, c1, wr_ * s1);
      wr_ = nw;
    }
    A1[((size_t)bx * 16 + ky) * 64 + c] = make_float2(sr, si);
  }
}

// Forward truncated DFT along x (H axis): rows (b*16+kx), cols (ky*64+c)
__global__ __launch_bounds__(256) void k_dft_x(const float2* __restrict__ A1,
    float* __restrict__ Ar, float* __restrict__ Ai) {
  __shared__ float2 sh[128 * 32];
  int b = blockIdx.x, ky = blockIdx.y, ch = blockIdx.z;
  int c0 = ch * 32;
  for (int i = threadIdx.x; i < 2048; i += 256) {
    int xx = i >> 4, u = (i & 15) * 2;
    *(float4*)&sh[xx * 32 + u] =
        *(const float4*)&A1[(((size_t)b * 128 + xx) * 16 + ky) * 64 + c0 + u];
  }
  __syncthreads();
  int cl = threadIdx.x & 31, kxg = threadIdx.x >> 5;
  float cs[2], sn[2], wr_[2], wi_[2], sr[2], si[2];
  #pragma unroll
  for (int q = 0; q < 2; ++q) {
    int kx = kxg + 8 * q;
    __sincosf(-TWO_PI_128 * (float)kx, &sn[q], &cs[q]);
    wr_[q] = 1.f; wi_[q] = 0.f; sr[q] = 0.f; si[q] = 0.f;
  }
  for (int xx = 0; xx < 128; ++xx) {
    float2 v = sh[xx * 32 + cl];
    #pragma unroll
    for (int q = 0; q < 2; ++q) {
      sr[q] = fmaf(v.x, wr_[q], sr[q]); sr[q] = fmaf(-v.y, wi_[q], sr[q]);
      si[q] = fmaf(v.x, wi_[q], si[q]); si[q] = fmaf(v.y, wr_[q], si[q]);
      float nw = wr_[q] * cs[q] - wi_[q] * sn[q];
      wi_[q] = fmaf(wi_[q], cs[q], wr_[q] * sn[q]);
      wr_[q] = nw;
    }
  }
  #pragma unroll
  for (int q = 0; q < 2; ++q) {
    int kx = kxg + 8 * q;
    int row = b * 16 + kx, col = ky * 64 + c0 + cl;
    Ar[row * 1024 + col] = sr[q];
    Ai[row * 1024 + col] = si[q];
  }
}

#define CMAC(cr, ci, ax, ay, bx, by)                 \
  cr = fmaf(ax, bx, cr); cr = fmaf(-(ay), by, cr);   \
  ci = fmaf(ax, by, ci); ci = fmaf(ay, bx, ci);

// Complex GEMM: C[256][1024] = A[256][1024] * B[1024][1024], K split in nz.
// K-split 2->4 when workspace permits: 512 blocks = 2/CU was grid-limited
// (2 barriers + global round-trip per K-tile, nothing to hide the stalls);
// 1024 blocks = 4/CU (LDS cap) doubles independent blocks per CU.
__global__ __launch_bounds__(256) void k_gemm(const float* __restrict__ Ar,
    const float* __restrict__ Ai, const float* __restrict__ Br,
    const float* __restrict__ Bi, float2* __restrict__ Cp, int kz, int nkt) {
  __shared__ float2 As[2][32][34];
  __shared__ float2 Bs[2][32][34];
  int tx = threadIdx.x & 15, ty = threadIdx.x >> 4;
  int row0 = blockIdx.y * 32, col0 = blockIdx.x * 32, kbase = blockIdx.z * kz;
  int ra = threadIdx.x >> 3, k4 = (threadIdx.x & 7) << 2;  // stage coords
  float4 arv, aiv, brv, biv;
  float cr00 = 0, cr01 = 0, cr10 = 0, cr11 = 0;
  float ci00 = 0, ci01 = 0, ci10 = 0, ci11 = 0;
  {
    int gia = (row0 + ra) * 1024 + kbase + k4;
    arv = *(const float4*)&Ar[gia];
    aiv = *(const float4*)&Ai[gia];
    int gib = (kbase + ra) * 1024 + col0 + k4;
    brv = *(const float4*)&Br[gib];
    biv = *(const float4*)&Bi[gib];
    *(float4*)&As[0][ra][k4]     = make_float4(arv.x, aiv.x, arv.y, aiv.y);
    *(float4*)&As[0][ra][k4 + 2] = make_float4(arv.z, aiv.z, arv.w, aiv.w);
    *(float4*)&Bs[0][ra][k4]     = make_float4(brv.x, biv.x, brv.y, biv.y);
    *(float4*)&Bs[0][ra][k4 + 2] = make_float4(brv.z, biv.z, brv.w, biv.w);
  }
  __syncthreads();
  for (int kt = 0; kt < nkt; ++kt) {
    if (kt < nkt - 1) {            // issue next-tile loads (overlap with compute)
      int k0 = kbase + (kt + 1) * 32;
      int gia = (row0 + ra) * 1024 + k0 + k4;
      arv = *(const float4*)&Ar[gia];
      aiv = *(const float4*)&Ai[gia];
      int gib = (k0 + ra) * 1024 + col0 + k4;
      brv = *(const float4*)&Br[gib];
      biv = *(const float4*)&Bi[gib];
    }
    int cur = kt & 1;
    #pragma unroll 8
    for (int kk2 = 0; kk2 < 16; ++kk2) {
      float4 a0p = *(const float4*)&As[cur][ty * 2][kk2 * 2];      // kk, kk+1
      float4 a1p = *(const float4*)&As[cur][ty * 2 + 1][kk2 * 2];
      float4 b0p = *(const float4*)&Bs[cur][kk2 * 2][tx * 2];      // j, j+1 @ kk
      float4 b1p = *(const float4*)&Bs[cur][kk2 * 2 + 1][tx * 2];  // j, j+1 @ kk+1
      CMAC(cr00, ci00, a0p.x, a0p.y, b0p.x, b0p.y)
      CMAC(cr01, ci01, a0p.x, a0p.y, b0p.z, b0p.w)
      CMAC(cr10, ci10, a1p.x, a1p.y, b0p.x, b0p.y)
      CMAC(cr11, ci11, a1p.x, a1p.y, b0p.z, b0p.w)
      CMAC(cr00, ci00, a0p.z, a0p.w, b1p.x, b1p.y)
      CMAC(cr01, ci01, a0p.z, a0p.w, b1p.z, b1p.w)
      CMAC(cr10, ci10, a1p.z, a1p.w, b1p.x, b1p.y)
      CMAC(cr11, ci11, a1p.z, a1p.w, b1p.z, b1p.w)
    }
    __syncthreads();               // all waves done reading buffer cur
    if (kt < nkt - 1) {
      int nxt = cur ^ 1;
      *(float4*)&As[nxt][ra][k4]     = make_float4(arv.x, aiv.x, arv.y, aiv.y);
      *(float4*)&As[nxt][ra][k4 + 2] = make_float4(arv.z, aiv.z, arv.w, aiv.w);
      *(float4*)&Bs[nxt][ra][k4]     = make_float4(brv.x, biv.x, brv.y, biv.y);
      *(float4*)&Bs[nxt][ra][k4 + 2] = make_float4(brv.z, biv.z, brv.w, biv.w);
    }
    __syncthreads();
  }
  int r = row0 + ty * 2, jj = col0 + tx * 2;
  size_t base = ((size_t)blockIdx.z * 256 + r) * 1024 + jj;
  Cp[base]        = make_float2(cr00, ci00);
  Cp[base + 1]    = make_float2(cr01, ci01);
  Cp[base + 1024] = make_float2(cr10, ci10);
  Cp[base + 1025] = make_float2(cr11, ci11);
}

// Inverse DFT along the W-frequency axis m -> y. Sums the nz K-split partials.
// T layout: [b][y][kx][c]
__global__ __launch_bounds__(256) void k_ifft_y(const float2* __restrict__ Cp,
                                                float2* __restrict__ T, int nz) {
  __shared__ float2 Cl[1024];
  int b = blockIdx.x >> 4, kx = blockIdx.x & 15;
  int row = b * 16 + kx;
  for (int i = threadIdx.x; i < 512; i += 256) {
    float4 s = *(const float4*)&Cp[(size_t)row * 1024 + i * 2];
    for (int z = 1; z < nz; ++z) {
      float4 v = *(const float4*)&Cp[(size_t)(256 * z + row) * 1024 + i * 2];
      s.x += v.x; s.y += v.y; s.z += v.z; s.w += v.w;
    }
    *(float4*)&Cl[i * 2] = s;
  }
  __syncthreads();
  int c = threadIdx.x & 63, yg = threadIdx.x >> 6;
  for (int y = yg; y < 128; y += 4) {
    float snv, csv;
    __sincosf(TWO_PI_128 * (float)y, &snv, &csv);
    float wr_ = 1.f, wi_ = 0.f, sr = 0.f, si = 0.f;
    #pragma unroll
    for (int ky = 0; ky < 16; ++ky) {
      float2 v = Cl[ky * 64 + c];
      sr = fmaf(v.x, wr_, sr); sr = fmaf(-v.y, wi_, sr);
      si = fmaf(v.x, wi_, si); si = fmaf(v.y, wr_, si);
      float nw = wr_ * csv - wi_ * snv;
      wi_ = fmaf(wi_, csv, wr_ * snv);
      wr_ = nw;
    }
    T[(((size_t)b * 128 + y) * 16 + kx) * 64 + c] = make_float2(sr, si);
  }
}

// Fused: inverse DFT along kx -> x (real part) + pointwise h@ww + wb + gelu.
// Block (b,y): reads/writes exactly the h elements at fixed (b,y).
// remap: ct in [0,8) (8 cc), xg in [0,32) (4 j), x = xg + 32*j.
// Per-j twiddle step is e^{2pi i kx*32/128} = i^kx -> compile-time swap/negate.
__global__ __launch_bounds__(256, 4) void k_layer_out(const float* hin,
    const float2* __restrict__ T, const float* __restrict__ ww,
    const float* __restrict__ wb, float* hout) {
  __shared__ alignas(16) float wwT[64 * 68];
  int b = blockIdx.x >> 7, y = blockIdx.x & 127;
  for (int i = threadIdx.x; i < 1024; i += 256) {
    int k = i >> 4, c4 = (i & 15) << 2;
    float4 v = *(const float4*)&ww[k * 64 + c4];
    wwT[(c4 + 0) * 68 + k] = v.x;
    wwT[(c4 + 1) * 68 + k] = v.y;
    wwT[(c4 + 2) * 68 + k] = v.z;
    wwT[(c4 + 3) * 68 + k] = v.w;
  }
  const float2* Tp = T + ((size_t)b * 128 + y) * 1024;
  __syncthreads();
  int ct = threadIdx.x & 7, xg = threadIdx.x >> 3;  // c = ct+8cc, x = xg+32j
  float acc[4][8];
  #pragma unroll
  for (int cc = 0; cc < 8; ++cc) {
    float bv = wb[ct + 8 * cc];
    #pragma unroll
    for (int j = 0; j < 4; ++j) acc[j][cc] = bv;
  }
  // x1: real part of sum_kx T[kx][c] * e^{+2pi i kx x/128}
  #pragma unroll
  for (int kx = 0; kx < 16; ++kx) {
    float tr[8], ti[8];
    #pragma unroll
    for (int cc = 0; cc < 8; ++cc) {
      float2 v = Tp[kx * 64 + ct + 8 * cc];
      tr[cc] = v.x; ti[cc] = v.y;
    }
    float s0v, c0v;
    __sincosf(TWO_PI_128 * (float)(kx * xg), &s0v, &c0v);
    float wr_ = c0v, wi_ = s0v;
    #pragma unroll
    for (int j = 0; j < 4; ++j) {
      #pragma unroll
      for (int cc = 0; cc < 8; ++cc) {
        acc[j][cc] = fmaf(tr[cc], wr_, acc[j][cc]);
        acc[j][cc] = fmaf(-ti[cc], wi_, acc[j][cc]);
      }
      // rotate (wr,wi) by i^kx -- kx is unroll-constant, folds at compile time
      float owr = wr_, owi = wi_;
      if ((kx & 3) == 1)      { wr_ = -owi; wi_ =  owr; }
      else if ((kx & 3) == 2) { wr_ = -owr; wi_ = -owi; }
      else if ((kx & 3) == 3) { wr_ =  owi; wi_ = -owr; }
    }
  }
  // x2: h @ ww, h read directly from global (rows x = xg+32j at fixed y)
  const float* hp = hin + (((size_t)b * 128 + xg) * 128 + y) * 64;
  #pragma unroll 1
  for (int kq = 0; kq < 64; kq += 4) {
    float4 wv[8];
    #pragma unroll
    for (int cc = 0; cc < 8; ++cc)
      wv[cc] = *(const float4*)&wwT[(ct + 8 * cc) * 68 + kq];
    #pragma unroll
    for (int j = 0; j < 4; ++j) {
      float4 hv = *(const float4*)&hp[(size_t)j * 262144 + kq];  // 32*128*64
      #pragma unroll
      for (int cc = 0; cc < 8; ++cc) {
        acc[j][cc] = fmaf(hv.x, wv[cc].x, acc[j][cc]);
        acc[j][cc] = fmaf(hv.y, wv[cc].y, acc[j][cc]);
        acc[j][cc] = fmaf(hv.z, wv[cc].z, acc[j][cc]);
        acc[j][cc] = fmaf(hv.w, wv[cc].w, acc[j][cc]);
      }
    }
  }
  __syncthreads();   // all hin reads drained (barrier waits vmcnt) before stores
  #pragma unroll
  for (int j = 0; j < 4; ++j) {
    int xx = xg + 32 * j;
    size_t base = (((size_t)b * 128 + xx) * 128 + y) * 64 + ct;
    #pragma unroll
    for (int cc = 0; cc < 8; ++cc)
      hout[base + 8 * cc] = gelu_f(acc[j][cc]);
  }
}

// Fused fc1 + gelu + fc2.  (round-2 structure, measured 81.6us: 128-row blocks,
// grid 2048; VALU-bound at ~72% -- the 64-row/grid-4096 variant regressed to
// 87us: doubled w1T staging work, and occupancy doesn't pay when VALU-bound.)
__global__ __launch_bounds__(256) void k_final(const float* __restrict__ h,
    const float* __restrict__ w1, const float* __restrict__ b1,
    const float* __restrict__ w2, const float* __restrict__ b2,
    float* __restrict__ out) {
  __shared__ alignas(16) float w1T[128 * 68];   // w1T[j][k]
  __shared__ alignas(16) float hl[128 * 68];    // hl[r][k]
  __shared__ float b1s[128];
  __shared__ float w2s[128];
  for (int i = threadIdx.x; i < 8192; i += 256) {
    int k = i >> 7, j = i & 127;
    w1T[j * 68 + k] = w1[i];
  }
  if (threadIdx.x < 128) {
    b1s[threadIdx.x] = b1[threadIdx.x];
    w2s[threadIdx.x] = w2[threadIdx.x];
  }
  int r0 = blockIdx.x * 128;
  for (int i = threadIdx.x; i < 2048; i += 256) {
    int r = i >> 4, kq = (i & 15) * 4;          // coalesced float4 row loads
    float4 v = *(const float4*)&h[(size_t)(r0 + r) * 64 + kq];
    *(float4*)&hl[r * 68 + kq] = v;
  }
  __syncthreads();
  int jt = threadIdx.x & 15, rg = threadIdx.x >> 4;  // j = jt+16*cc, r = rg+16*ii
  float acc[8][8];   // [ii][cc]
  #pragma unroll
  for (int cc = 0; cc < 8; ++cc) {
    float bv = b1s[jt + 16 * cc];
    #pragma unroll
    for (int ii = 0; ii < 8; ++ii) acc[ii][cc] = bv;
  }
  #pragma unroll 1
  for (int kq = 0; kq < 64; kq += 4) {
    float4 hv[8];
    #pragma unroll
    for (int ii = 0; ii < 8; ++ii)
      hv[ii] = *(const float4*)&hl[(rg + 16 * ii) * 68 + kq];
    #pragma unroll
    for (int cc = 0; cc < 8; ++cc) {
      float4 wv = *(const float4*)&w1T[(jt + 16 * cc) * 68 + kq];
      #pragma unroll
      for (int ii = 0; ii < 8; ++ii) {
        acc[ii][cc] = fmaf(hv[ii].x, wv.x, acc[ii][cc]);
        acc[ii][cc] = fmaf(hv[ii].y, wv.y, acc[ii][cc]);
        acc[ii][cc] = fmaf(hv[ii].z, wv.z, acc[ii][cc]);
        acc[ii][cc] = fmaf(hv[ii].w, wv.w, acc[ii][cc]);
      }
    }
  }
  float b2v = b2[0];
  #pragma unroll
  for (int ii = 0; ii < 8; ++ii) {
    float part = 0.f;
    #pragma unroll
    for (int cc = 0; cc < 8; ++cc)
      part = fmaf(gelu_f(acc[ii][cc]), w2s[jt + 16 * cc], part);
    part += __shfl_xor(part, 1, 64);
    part += __shfl_xor(part, 2, 64);
    part += __shfl_xor(part, 4, 64);
    part += __shfl_xor(part, 8, 64);
    if (jt == 0) out[r0 + rg + 16 * ii] = part + b2v;
  }
}

extern "C" void kernel_launch(void* const* d_in, const int* in_sizes, int n_in,
                              void* d_out, int out_size, void* d_ws, size_t ws_size,
                              hipStream_t stream) {
  (void)in_sizes; (void)n_in; (void)out_size;
  const float* x      = (const float*)d_in[0];
  const float* fcin_w = (const float*)d_in[1];
  const float* fcin_b = (const float*)d_in[2];
  const float* wr     = (const float*)d_in[3];
  const float* wi     = (const float*)d_in[4];
  const float* ww     = (const float*)d_in[5];
  const float* wb     = (const float*)d_in[6];
  const float* fc1_w  = (const float*)d_in[7];
  const float* fc1_b  = (const float*)d_in[8];
  const float* fc2_w  = (const float*)d_in[9];
  const float* fc2_b  = (const float*)d_in[10];
  float* out = (float*)d_out;

  // workspace layout (floats): base 22.5M + Cp nz*0.5M
  float*  hA = (float*)d_ws;              // 16,777,216
  float2* A1 = (float2*)(hA + 16777216);  // 2,097,152 float2 (A1 fwd / T bwd alias)
  float*  Ar = (float*)(A1 + 2097152);    // 262,144
  float*  Ai = Ar + 262144;               // 262,144
  float*  Br = Ai + 262144;               // 1,048,576
  float*  Bi = Br + 1048576;              // 1,048,576
  float2* Cp = (float2*)(Bi + 1048576);   // nz*262,144 float2 (K-split partials)

  // K-split factor: 4 if the workspace can hold 4 partials (102.8 MB), else
  // the validated 2-partial layout (98.6 MB).
  const size_t base_floats = 16777216 + 4194304 + 262144 * 2 + 1048576 * 2;
  int nz = (ws_size >= (base_floats + 4 * 524288) * sizeof(float)) ? 4 : 2;
  int kz = 1024 / nz, nkt = kz / 32;

  k_fc_in<<<16384, 256, 0, stream>>>(x, fcin_w, fcin_b, hA);
  for (int l = 0; l < 4; ++l) {
    k_prep<<<4096, 256, 0, stream>>>(wr + (size_t)l * 8388608,
                                     wi + (size_t)l * 8388608, Br, Bi);
    k_dft_y<<<2048, 256, 0, stream>>>(hA, A1);
    k_dft_x<<<dim3(16, 16, 2), 256, 0, stream>>>(A1, Ar, Ai);
    k_gemm<<<dim3(32, 8, nz), 256, 0, stream>>>(Ar, Ai, Br, Bi, Cp, kz, nkt);
    k_ifft_y<<<256, 256, 0, stream>>>(Cp, A1, nz);   // A1 now holds T
    k_layer_out<<<2048, 256, 0, stream>>>(hA, A1, ww + (size_t)l * 4096,
                                          wb + (size_t)l * 64, hA);
  }
  k_final<<<2048, 256, 0, stream>>>(hA, fc1_w, fc1_b, fc2_w, fc2_b, out);
}